// Round 7
// baseline (209.320 us; speedup 1.0000x reference)
//
#include <hip/hip_runtime.h>
#include <math.h>

#define BN 2
#define SN 1024
#define TN 1024
#define DS 128
#define DT 64
#define HN 64
#define LN_EPS 1e-5f

typedef float v2f __attribute__((ext_vector_type(2)));

__device__ __forceinline__ float wave_sum(float v) {
#pragma unroll
  for (int m = 32; m >= 1; m >>= 1) v += __shfl_xor(v, m, 64);
  return v;
}

// ---------------- Kernel 1: both adapters in one launch ----------------
__global__ __launch_bounds__(256) void k_adapters(
    const float* __restrict__ src, const float* __restrict__ tgt,
    const float* __restrict__ sW1, const float* __restrict__ sb1,
    const float* __restrict__ sg, const float* __restrict__ sbeta,
    const float* __restrict__ sW2, const float* __restrict__ sb2,
    const float* __restrict__ tW1, const float* __restrict__ tb1,
    const float* __restrict__ tg, const float* __restrict__ tbeta,
    const float* __restrict__ tW2, const float* __restrict__ tb2,
    const float* __restrict__ cW, const float* __restrict__ cb,
    float* __restrict__ s_ad, float* __restrict__ sc, float* __restrict__ sstats,
    float* __restrict__ t_ad, float* __restrict__ tc, float* __restrict__ tstats)
{
  __shared__ float xbuf[4][DS];
  __shared__ float rbuf[4][HN];
  int w = threadIdx.x >> 6, lane = threadIdx.x & 63;

  if (blockIdx.x < 512) {
    int row = blockIdx.x * 4 + w;  // 0..2047
    xbuf[w][lane]      = src[row * DS + lane];
    xbuf[w][lane + 64] = src[row * DS + 64 + lane];
    float a0 = 0.f, a1 = 0.f, a2_ = 0.f, a3 = 0.f;
#pragma unroll 8
    for (int k = 0; k < DS; k += 4) {
      a0  = fmaf(xbuf[w][k + 0], sW1[(k + 0) * HN + lane], a0);
      a1  = fmaf(xbuf[w][k + 1], sW1[(k + 1) * HN + lane], a1);
      a2_ = fmaf(xbuf[w][k + 2], sW1[(k + 2) * HN + lane], a2_);
      a3  = fmaf(xbuf[w][k + 3], sW1[(k + 3) * HN + lane], a3);
    }
    float h1 = ((a0 + a1) + (a2_ + a3)) + sb1[lane];
    float s1 = wave_sum(h1), s2 = wave_sum(h1 * h1);
    float m = s1 * (1.f / HN);
    float var = s2 * (1.f / HN) - m * m;
    float r = fmaxf(0.f, (h1 - m) * rsqrtf(var + LN_EPS) * sg[lane] + sbeta[lane]);
    rbuf[w][lane] = r;
    float b0 = 0.f, b1 = 0.f, b2 = 0.f, b3 = 0.f;
#pragma unroll 4
    for (int j = 0; j < HN; j += 4) {
      b0 = fmaf(rbuf[w][j + 0], sW2[(j + 0) * HN + lane], b0);
      b1 = fmaf(rbuf[w][j + 1], sW2[(j + 1) * HN + lane], b1);
      b2 = fmaf(rbuf[w][j + 2], sW2[(j + 2) * HN + lane], b2);
      b3 = fmaf(rbuf[w][j + 3], sW2[(j + 3) * HN + lane], b3);
    }
    float a2 = ((b0 + b1) + (b2 + b3)) + sb2[lane];
    s_ad[row * HN + lane] = a2;
    rbuf[w][lane] = a2;
    float c0 = 0.f, c1 = 0.f, c2 = 0.f, c3 = 0.f;
#pragma unroll 4
    for (int j = 0; j < HN; j += 4) {
      c0 = fmaf(rbuf[w][j + 0], cW[(HN + j + 0) * HN + lane], c0);
      c1 = fmaf(rbuf[w][j + 1], cW[(HN + j + 1) * HN + lane], c1);
      c2 = fmaf(rbuf[w][j + 2], cW[(HN + j + 2) * HN + lane], c2);
      c3 = fmaf(rbuf[w][j + 3], cW[(HN + j + 3) * HN + lane], c3);
    }
    float scv = (c0 + c1) + (c2 + c3);
    sc[row * HN + lane] = scv;
    float bs = wave_sum(scv), qs = wave_sum(scv * scv);
    if (lane == 0) { sstats[row * 2] = bs; sstats[row * 2 + 1] = qs; }
  } else {
    int row = (blockIdx.x - 512) * 4 + w;  // 0..2047
    xbuf[w][lane] = tgt[row * DT + lane];
    float a0 = 0.f, a1 = 0.f, a2_ = 0.f, a3 = 0.f;
#pragma unroll 4
    for (int k = 0; k < DT; k += 4) {
      a0  = fmaf(xbuf[w][k + 0], tW1[(k + 0) * HN + lane], a0);
      a1  = fmaf(xbuf[w][k + 1], tW1[(k + 1) * HN + lane], a1);
      a2_ = fmaf(xbuf[w][k + 2], tW1[(k + 2) * HN + lane], a2_);
      a3  = fmaf(xbuf[w][k + 3], tW1[(k + 3) * HN + lane], a3);
    }
    float h1 = ((a0 + a1) + (a2_ + a3)) + tb1[lane];
    float s1 = wave_sum(h1), s2 = wave_sum(h1 * h1);
    float m = s1 * (1.f / HN);
    float var = s2 * (1.f / HN) - m * m;
    float r = fmaxf(0.f, (h1 - m) * rsqrtf(var + LN_EPS) * tg[lane] + tbeta[lane]);
    rbuf[w][lane] = r;
    float b0 = 0.f, b1 = 0.f, b2 = 0.f, b3 = 0.f;
#pragma unroll 4
    for (int j = 0; j < HN; j += 4) {
      b0 = fmaf(rbuf[w][j + 0], tW2[(j + 0) * HN + lane], b0);
      b1 = fmaf(rbuf[w][j + 1], tW2[(j + 1) * HN + lane], b1);
      b2 = fmaf(rbuf[w][j + 2], tW2[(j + 2) * HN + lane], b2);
      b3 = fmaf(rbuf[w][j + 3], tW2[(j + 3) * HN + lane], b3);
    }
    float a2 = ((b0 + b1) + (b2 + b3)) + tb2[lane];
    t_ad[row * HN + lane] = a2;
    float asum = wave_sum(a2);
    float gate = 1.f / (1.f + __expf(-asum * (1.f / HN)));
    rbuf[w][lane] = a2;
    float c0 = 0.f, c1 = 0.f, c2 = 0.f, c3 = 0.f;
#pragma unroll 4
    for (int j = 0; j < HN; j += 4) {
      c0 = fmaf(rbuf[w][j + 0], cW[(j + 0) * HN + lane], c0);
      c1 = fmaf(rbuf[w][j + 1], cW[(j + 1) * HN + lane], c1);
      c2 = fmaf(rbuf[w][j + 2], cW[(j + 2) * HN + lane], c2);
      c3 = fmaf(rbuf[w][j + 3], cW[(j + 3) * HN + lane], c3);
    }
    float tcv = ((c0 + c1) + (c2 + c3)) + cb[lane];
    tc[row * HN + lane] = tcv;
    float A = wave_sum(tcv), Q = wave_sum(tcv * tcv);
    if (lane == 0) { tstats[row * 3] = A; tstats[row * 3 + 1] = Q; tstats[row * 3 + 2] = gate; }
  }
}

// ---------------- Kernel 2: scores v7 ----------------
// g-major padded LDS tile: slot (g, srow) at float4 index g*66 + srow.
// Reads: vaddr = lane*16 (constant), 16 immediate offsets g*1056 -> zero
// addressing VALU, 2-way bank aliasing (free). Double-buffered chunks of
// 64 s; one t per wave (tc/cg/cbeta/simW on the scalar path); pk math.
#define GSTRIDE 264   // dwords per g-block (66 float4)
#define CHUNKDW (16 * GSTRIDE)
__global__ __launch_bounds__(512, 8) void k_scores(
    const float* __restrict__ cg, const float* __restrict__ cbeta,
    const float* __restrict__ simW, const float* __restrict__ simb,
    const float* __restrict__ sc, const float* __restrict__ sstats,
    const float* __restrict__ tc, const float* __restrict__ tstats,
    float* __restrict__ out_scores)
{
  __shared__ float tile[2 * CHUNKDW];   // 2 x 16.9 KB
  int tid = threadIdx.x;
  int w = tid >> 6, lane = tid & 63;
  int sblk = blockIdx.x & 3;                 // 4 s-blocks of 256
  int tblk = (blockIdx.x >> 2) & 127;        // 128 t-blocks of 8
  int b    = blockIdx.x >> 9;
  int t = tblk * 8 + w;
  int rt = __builtin_amdgcn_readfirstlane(b * TN + t);

  float A  = tstats[rt * 3 + 0];
  float Qt = tstats[rt * 3 + 1];
  const float4* tcq = (const float4*)(tc + rt * HN);   // wave-uniform
  const float4* cgq = (const float4*)cg;
  const float4* cbq = (const float4*)cbeta;
  const float4* swq = (const float4*)simW;
  float simb0 = simb[0];

  const float4* scg = (const float4*)(sc + b * SN * HN);
  int s0 = sblk * 256;

  // staging mapping: thread -> two (srow, g) cells; dest dword fixed/thread
  int j0 = tid, j1 = 512 + tid;
  int r0 = j0 >> 4, g0 = j0 & 15;
  int r1 = j1 >> 4, g1 = j1 & 15;
  int d0 = g0 * GSTRIDE + r0 * 4;
  int d1 = g1 * GSTRIDE + r1 * 4;

  // prologue: chunk 0 -> buf 0
  {
    float4 v0 = scg[(s0 + r0) * 16 + g0];
    float4 v1 = scg[(s0 + r1) * 16 + g1];
    *(float4*)&tile[d0] = v0;
    *(float4*)&tile[d1] = v1;
  }
  __syncthreads();

#pragma unroll 1
  for (int c = 0; c < 4; ++c) {
    // prefetch chunk c+1 into regs
    float4 p0, p1;
    if (c < 3) {
      int sn = s0 + (c + 1) * 64;
      p0 = scg[(sn + r0) * 16 + g0];
      p1 = scg[(sn + r1) * 16 + g1];
    }

    const float* tb_ = &tile[(c & 1) * CHUNKDW + lane * 4];
    int s = s0 + c * 64 + lane;
    float2 bq = *(const float2*)&sstats[(b * SN + s) * 2];

    // pass 1: D = sum_h tc_h * sc_h  (16 immediate-offset ds_read_b128)
    v2f D2 = {0.f, 0.f};
#pragma unroll
    for (int g = 0; g < 16; ++g) {
      float4 v = *(const float4*)&tb_[g * GSTRIDE];
      float4 t4 = tcq[g];
      v2f vlo = {v.x, v.y}, vhi = {v.z, v.w};
      v2f tlo = {t4.x, t4.y}, thi = {t4.z, t4.w};
      D2 = __builtin_elementwise_fma(tlo, vlo, D2);
      D2 = __builtin_elementwise_fma(thi, vhi, D2);
    }
    float D = D2.x + D2.y;
    float mean  = (A + bq.x) * (1.f / HN);
    float e2    = (Qt + bq.y + 2.f * D) * (1.f / HN);
    float var   = e2 - mean * mean;
    float alpha = rsqrtf(var + LN_EPS);

    v2f m2 = {mean, mean};
    v2f a2 = {alpha, alpha};
    v2f zero2 = {0.f, 0.f};
    v2f dot2 = {0.f, 0.f};

    // pass 2 (packed)
#pragma unroll
    for (int g = 0; g < 16; ++g) {
      float4 v  = *(const float4*)&tb_[g * GSTRIDE];
      float4 t4 = tcq[g];
      float4 c4 = cgq[g];
      float4 b4 = cbq[g];
      float4 w4 = swq[g];
      {
        v2f vv = {v.x, v.y}, tt = {t4.x, t4.y};
        v2f cc = {c4.x, c4.y}, bb = {b4.x, b4.y}, ss = {w4.x, w4.y};
        v2f u = vv + tt;
        v2f z = u - m2;
        v2f P = a2 * cc;
        v2f n = __builtin_elementwise_fma(z, P, bb);
        v2f r = __builtin_elementwise_max(n, zero2);
        dot2 = __builtin_elementwise_fma(r, ss, dot2);
      }
      {
        v2f vv = {v.z, v.w}, tt = {t4.z, t4.w};
        v2f cc = {c4.z, c4.w}, bb = {b4.z, b4.w}, ss = {w4.z, w4.w};
        v2f u = vv + tt;
        v2f z = u - m2;
        v2f P = a2 * cc;
        v2f n = __builtin_elementwise_fma(z, P, bb);
        v2f r = __builtin_elementwise_max(n, zero2);
        dot2 = __builtin_elementwise_fma(r, ss, dot2);
      }
    }
    float dot = dot2.x + dot2.y;
    float score = 1.f / (1.f + __expf(-(dot + simb0)));
    out_scores[rt * SN + s] = score;

    // write prefetched chunk into the other buffer, then barrier
    if (c < 3) {
      int dst = ((c + 1) & 1) * CHUNKDW;
      *(float4*)&tile[dst + d0] = p0;
      *(float4*)&tile[dst + d1] = p1;
    }
    __syncthreads();
  }
}

// ---------------- Kernel 3a: partial transfer (split-s) ----------------
__global__ __launch_bounds__(256, 4) void k_xfer(
    const float* __restrict__ scores, const float* __restrict__ s_ad,
    float* __restrict__ xpart, float* __restrict__ epart)
{
  __shared__ float eLDS[4][16][64];
  __shared__ float part[4][16][64];
  __shared__ float esum[4][16];
  int tid = threadIdx.x;
  int w = __builtin_amdgcn_readfirstlane(tid >> 6);
  int lane = tid & 63;
  int sblk = blockIdx.x & 3;
  int tblk = (blockIdx.x >> 2) & 63;
  int b    = blockIdx.x >> 8;
  int t0 = tblk * 16;
  int soff = sblk * 256 + w * 64;

#pragma unroll 4
  for (int t = 0; t < 16; ++t) {
    int rt = __builtin_amdgcn_readfirstlane(b * TN + t0 + t);
    float ev = __expf(scores[rt * SN + soff + lane]);
    eLDS[w][t][lane] = ev;
    float es = wave_sum(ev);
    if (lane == 0) esum[w][t] = es;
  }

  const float* sadb = s_ad + b * SN * HN;
  float acc[16];
#pragma unroll
  for (int t = 0; t < 16; ++t) acc[t] = 0.f;
#pragma unroll 4
  for (int si4 = 0; si4 < 16; ++si4) {
    int sbase = soff + si4 * 4;
    float sv0 = sadb[(sbase + 0) * HN + lane];
    float sv1 = sadb[(sbase + 1) * HN + lane];
    float sv2 = sadb[(sbase + 2) * HN + lane];
    float sv3 = sadb[(sbase + 3) * HN + lane];
#pragma unroll
    for (int t = 0; t < 16; ++t) {
      float4 e4 = *(const float4*)&eLDS[w][t][si4 * 4];
      acc[t] = fmaf(e4.x, sv0, acc[t]);
      acc[t] = fmaf(e4.y, sv1, acc[t]);
      acc[t] = fmaf(e4.z, sv2, acc[t]);
      acc[t] = fmaf(e4.w, sv3, acc[t]);
    }
  }

#pragma unroll
  for (int t = 0; t < 16; ++t) part[w][t][lane] = acc[t];
  __syncthreads();
#pragma unroll
  for (int k = 0; k < 4; ++k) {
    int c2 = tid + k * 256;
    int t = c2 >> 6, h = c2 & 63;
    float sum = part[0][t][h] + part[1][t][h] + part[2][t][h] + part[3][t][h];
    int rt = b * TN + t0 + t;
    xpart[(rt * 4 + sblk) * HN + h] = sum;
  }
  if (tid < 16) {
    float es = esum[0][tid] + esum[1][tid] + esum[2][tid] + esum[3][tid];
    int rt = b * TN + t0 + tid;
    epart[rt * 4 + sblk] = es;
  }
}

// ---------------- Kernel 3b: final combine + gate ----------------
__global__ __launch_bounds__(256) void k_final(
    const float* __restrict__ xpart, const float* __restrict__ epart,
    const float* __restrict__ t_ad, const float* __restrict__ tstats,
    float* __restrict__ out_adapted)
{
  int tid = threadIdx.x;
  int tl = tid >> 6, h = tid & 63;
  int rt = blockIdx.x * 4 + tl;       // 0..2047
  float x = xpart[(rt * 4 + 0) * HN + h] + xpart[(rt * 4 + 1) * HN + h]
          + xpart[(rt * 4 + 2) * HN + h] + xpart[(rt * 4 + 3) * HN + h];
  float es = epart[rt * 4 + 0] + epart[rt * 4 + 1]
           + epart[rt * 4 + 2] + epart[rt * 4 + 3];
  float tr = x / es;
  float gate = tstats[rt * 3 + 2];
  float tad = t_ad[rt * HN + h];
  out_adapted[rt * HN + h] = tad * (1.f - gate) + tr * gate;
}

extern "C" void kernel_launch(void* const* d_in, const int* in_sizes, int n_in,
                              void* d_out, int out_size, void* d_ws, size_t ws_size,
                              hipStream_t stream) {
  const float* src   = (const float*)d_in[0];
  const float* tgt   = (const float*)d_in[1];
  const float* sW1   = (const float*)d_in[2];
  const float* sb1   = (const float*)d_in[3];
  const float* sg    = (const float*)d_in[4];
  const float* sbeta = (const float*)d_in[5];
  const float* sW2   = (const float*)d_in[6];
  const float* sb2   = (const float*)d_in[7];
  const float* tW1   = (const float*)d_in[8];
  const float* tb1   = (const float*)d_in[9];
  const float* tg    = (const float*)d_in[10];
  const float* tbeta = (const float*)d_in[11];
  const float* tW2   = (const float*)d_in[12];
  const float* tb2   = (const float*)d_in[13];
  const float* cW    = (const float*)d_in[14];
  const float* cb    = (const float*)d_in[15];
  const float* cg    = (const float*)d_in[16];
  const float* cbeta = (const float*)d_in[17];
  const float* simW  = (const float*)d_in[18];
  const float* simb  = (const float*)d_in[19];

  float* ws     = (float*)d_ws;
  float* s_ad   = ws;               // 131072
  float* sc     = ws + 131072;      // 131072
  float* sstats = ws + 262144;      // 4096
  float* t_ad   = ws + 266240;      // 131072
  float* tc     = ws + 397312;      // 131072
  float* tstats = ws + 528384;      // 6144
  float* xpart  = ws + 534528;      // 524288
  float* epart  = ws + 1058816;     // 8192

  float* out_adapted = (float*)d_out;            // B*T*H
  float* out_scores  = (float*)d_out + 131072;   // B*T*S

  hipLaunchKernelGGL(k_adapters, dim3(1024), dim3(256), 0, stream,
                     src, tgt, sW1, sb1, sg, sbeta, sW2, sb2,
                     tW1, tb1, tg, tbeta, tW2, tb2, cW, cb,
                     s_ad, sc, sstats, t_ad, tc, tstats);
  hipLaunchKernelGGL(k_scores, dim3(BN * 128 * 4), dim3(512), 0, stream,
                     cg, cbeta, simW, simb, sc, sstats, tc, tstats, out_scores);
  hipLaunchKernelGGL(k_xfer, dim3(BN * 64 * 4), dim3(256), 0, stream,
                     out_scores, s_ad, xpart, epart);
  hipLaunchKernelGGL(k_final, dim3(512), dim3(256), 0, stream,
                     xpart, epart, t_ad, tstats, out_adapted);
}

// Round 8
// 169.391 us; speedup vs baseline: 1.2357x; 1.2357x over previous
//
#include <hip/hip_runtime.h>
#include <math.h>

#define BN 2
#define SN 1024
#define TN 1024
#define DS 128
#define DT 64
#define HN 64
#define LN_EPS 1e-5f

typedef float v2f __attribute__((ext_vector_type(2)));

__device__ __forceinline__ float wave_sum(float v) {
#pragma unroll
  for (int m = 32; m >= 1; m >>= 1) v += __shfl_xor(v, m, 64);
  return v;
}

__device__ __forceinline__ v2f lo2(float4 v) { v2f r = {v.x, v.y}; return r; }
__device__ __forceinline__ v2f hi2(float4 v) { v2f r = {v.z, v.w}; return r; }

// ---------------- Kernel 1: both adapters in one launch ----------------
__global__ __launch_bounds__(256) void k_adapters(
    const float* __restrict__ src, const float* __restrict__ tgt,
    const float* __restrict__ sW1, const float* __restrict__ sb1,
    const float* __restrict__ sg, const float* __restrict__ sbeta,
    const float* __restrict__ sW2, const float* __restrict__ sb2,
    const float* __restrict__ tW1, const float* __restrict__ tb1,
    const float* __restrict__ tg, const float* __restrict__ tbeta,
    const float* __restrict__ tW2, const float* __restrict__ tb2,
    const float* __restrict__ cW, const float* __restrict__ cb,
    float* __restrict__ s_ad, float* __restrict__ sc, float* __restrict__ sstats,
    float* __restrict__ t_ad, float* __restrict__ tc, float* __restrict__ tstats)
{
  __shared__ float xbuf[4][DS];
  __shared__ float rbuf[4][HN];
  int w = threadIdx.x >> 6, lane = threadIdx.x & 63;

  if (blockIdx.x < 512) {
    int row = blockIdx.x * 4 + w;  // 0..2047
    xbuf[w][lane]      = src[row * DS + lane];
    xbuf[w][lane + 64] = src[row * DS + 64 + lane];
    float a0 = 0.f, a1 = 0.f, a2_ = 0.f, a3 = 0.f;
#pragma unroll 8
    for (int k = 0; k < DS; k += 4) {
      a0  = fmaf(xbuf[w][k + 0], sW1[(k + 0) * HN + lane], a0);
      a1  = fmaf(xbuf[w][k + 1], sW1[(k + 1) * HN + lane], a1);
      a2_ = fmaf(xbuf[w][k + 2], sW1[(k + 2) * HN + lane], a2_);
      a3  = fmaf(xbuf[w][k + 3], sW1[(k + 3) * HN + lane], a3);
    }
    float h1 = ((a0 + a1) + (a2_ + a3)) + sb1[lane];
    float s1 = wave_sum(h1), s2 = wave_sum(h1 * h1);
    float m = s1 * (1.f / HN);
    float var = s2 * (1.f / HN) - m * m;
    float r = fmaxf(0.f, (h1 - m) * rsqrtf(var + LN_EPS) * sg[lane] + sbeta[lane]);
    rbuf[w][lane] = r;
    float b0 = 0.f, b1 = 0.f, b2 = 0.f, b3 = 0.f;
#pragma unroll 4
    for (int j = 0; j < HN; j += 4) {
      b0 = fmaf(rbuf[w][j + 0], sW2[(j + 0) * HN + lane], b0);
      b1 = fmaf(rbuf[w][j + 1], sW2[(j + 1) * HN + lane], b1);
      b2 = fmaf(rbuf[w][j + 2], sW2[(j + 2) * HN + lane], b2);
      b3 = fmaf(rbuf[w][j + 3], sW2[(j + 3) * HN + lane], b3);
    }
    float a2 = ((b0 + b1) + (b2 + b3)) + sb2[lane];
    s_ad[row * HN + lane] = a2;
    rbuf[w][lane] = a2;
    float c0 = 0.f, c1 = 0.f, c2 = 0.f, c3 = 0.f;
#pragma unroll 4
    for (int j = 0; j < HN; j += 4) {
      c0 = fmaf(rbuf[w][j + 0], cW[(HN + j + 0) * HN + lane], c0);
      c1 = fmaf(rbuf[w][j + 1], cW[(HN + j + 1) * HN + lane], c1);
      c2 = fmaf(rbuf[w][j + 2], cW[(HN + j + 2) * HN + lane], c2);
      c3 = fmaf(rbuf[w][j + 3], cW[(HN + j + 3) * HN + lane], c3);
    }
    float scv = (c0 + c1) + (c2 + c3);
    sc[row * HN + lane] = scv;
    float bs = wave_sum(scv), qs = wave_sum(scv * scv);
    if (lane == 0) { sstats[row * 2] = bs; sstats[row * 2 + 1] = qs; }
  } else {
    int row = (blockIdx.x - 512) * 4 + w;  // 0..2047
    xbuf[w][lane] = tgt[row * DT + lane];
    float a0 = 0.f, a1 = 0.f, a2_ = 0.f, a3 = 0.f;
#pragma unroll 4
    for (int k = 0; k < DT; k += 4) {
      a0  = fmaf(xbuf[w][k + 0], tW1[(k + 0) * HN + lane], a0);
      a1  = fmaf(xbuf[w][k + 1], tW1[(k + 1) * HN + lane], a1);
      a2_ = fmaf(xbuf[w][k + 2], tW1[(k + 2) * HN + lane], a2_);
      a3  = fmaf(xbuf[w][k + 3], tW1[(k + 3) * HN + lane], a3);
    }
    float h1 = ((a0 + a1) + (a2_ + a3)) + tb1[lane];
    float s1 = wave_sum(h1), s2 = wave_sum(h1 * h1);
    float m = s1 * (1.f / HN);
    float var = s2 * (1.f / HN) - m * m;
    float r = fmaxf(0.f, (h1 - m) * rsqrtf(var + LN_EPS) * tg[lane] + tbeta[lane]);
    rbuf[w][lane] = r;
    float b0 = 0.f, b1 = 0.f, b2 = 0.f, b3 = 0.f;
#pragma unroll 4
    for (int j = 0; j < HN; j += 4) {
      b0 = fmaf(rbuf[w][j + 0], tW2[(j + 0) * HN + lane], b0);
      b1 = fmaf(rbuf[w][j + 1], tW2[(j + 1) * HN + lane], b1);
      b2 = fmaf(rbuf[w][j + 2], tW2[(j + 2) * HN + lane], b2);
      b3 = fmaf(rbuf[w][j + 3], tW2[(j + 3) * HN + lane], b3);
    }
    float a2 = ((b0 + b1) + (b2 + b3)) + tb2[lane];
    t_ad[row * HN + lane] = a2;
    float asum = wave_sum(a2);
    float gate = 1.f / (1.f + __expf(-asum * (1.f / HN)));
    rbuf[w][lane] = a2;
    float c0 = 0.f, c1 = 0.f, c2 = 0.f, c3 = 0.f;
#pragma unroll 4
    for (int j = 0; j < HN; j += 4) {
      c0 = fmaf(rbuf[w][j + 0], cW[(j + 0) * HN + lane], c0);
      c1 = fmaf(rbuf[w][j + 1], cW[(j + 1) * HN + lane], c1);
      c2 = fmaf(rbuf[w][j + 2], cW[(j + 2) * HN + lane], c2);
      c3 = fmaf(rbuf[w][j + 3], cW[(j + 3) * HN + lane], c3);
    }
    float tcv = ((c0 + c1) + (c2 + c3)) + cb[lane];
    tc[row * HN + lane] = tcv;
    float A = wave_sum(tcv), Q = wave_sum(tcv * tcv);
    if (lane == 0) { tstats[row * 3] = A; tstats[row * 3 + 1] = Q; tstats[row * 3 + 2] = gate; }
  }
}

// ---------------- Kernel 2: scores v8 ----------------
// Row-major LDS with stride 68 dwords (+4 pad): per-lane base = lane*272B,
// per-g IMMEDIATE offsets g*16B (zero addressing VALU); bank quad start
// 4*(lane+g) mod 32 -> 8 disjoint-quad lanes per cycle, conflict-free b128.
// Each wave handles TWO t (amortizes the register-cached s-row over both
// passes x both t = 4 uses/load). q0..q15 kept in VGPRs via
// amdgpu_waves_per_eu(4,4) (stops the backend's 64-VGPR occupancy target).
#define ROWDW 68
#define CHUNKDW (64 * ROWDW)

__global__ __attribute__((amdgpu_flat_work_group_size(512, 512)))
__attribute__((amdgpu_waves_per_eu(4, 4)))
void k_scores(
    const float* __restrict__ cg, const float* __restrict__ cbeta,
    const float* __restrict__ simW, const float* __restrict__ simb,
    const float* __restrict__ sc, const float* __restrict__ sstats,
    const float* __restrict__ tc, const float* __restrict__ tstats,
    float* __restrict__ out_scores)
{
  __shared__ float tile[2 * CHUNKDW];   // 2 x 17.4 KB
  int tid = threadIdx.x;
  int w = tid >> 6, lane = tid & 63;
  int sblk = blockIdx.x & 3;                 // 4 s-blocks of 256
  int tblk = (blockIdx.x >> 2) & 63;         // 64 t-blocks of 16
  int b    = blockIdx.x >> 8;
  int t0 = tblk * 16 + w * 2;
  int rt0 = __builtin_amdgcn_readfirstlane(b * TN + t0);
  int rt1 = rt0 + 1;

  float A0  = tstats[rt0 * 3 + 0];
  float Qt0 = tstats[rt0 * 3 + 1];
  float A1  = tstats[rt1 * 3 + 0];
  float Qt1 = tstats[rt1 * 3 + 1];
  const float4* tq0 = (const float4*)(tc + rt0 * HN);  // wave-uniform
  const float4* tq1 = (const float4*)(tc + rt1 * HN);
  const float4* cgq = (const float4*)cg;
  const float4* cbq = (const float4*)cbeta;
  const float4* swq = (const float4*)simW;
  float simb0 = simb[0];

  const float4* scg = (const float4*)(sc + b * SN * HN);
  int s0 = sblk * 256;

  // staging: thread -> cells (r0s,gs) and (r0s+32,gs); dest dword r*68+g*4
  int r0s = tid >> 4, gs = tid & 15;
  int d0 = r0s * ROWDW + gs * 4;
  int d1 = d0 + 32 * ROWDW;

  // prologue: chunk 0 -> buf 0
  {
    float4 v0 = scg[(s0 + r0s) * 16 + gs];
    float4 v1 = scg[(s0 + r0s + 32) * 16 + gs];
    *(float4*)&tile[d0] = v0;
    *(float4*)&tile[d1] = v1;
  }
  __syncthreads();

  const v2f zero2 = {0.f, 0.f};

#pragma unroll 1
  for (int c = 0; c < 4; ++c) {
    float4 p0, p1;
    if (c < 3) {
      int sn = s0 + (c + 1) * 64;
      p0 = scg[(sn + r0s) * 16 + gs];
      p1 = scg[(sn + r0s + 32) * 16 + gs];
    }

    const float* tb_ = &tile[(c & 1) * CHUNKDW + lane * ROWDW];
    int s = s0 + c * 64 + lane;
    float2 bq = *(const float2*)&sstats[(b * SN + s) * 2];

    // register-cache the s-row: 16 immediate-offset ds_read_b128
    float4 q0, q1, q2, q3, q4, q5, q6, q7, q8, q9, q10, q11, q12, q13, q14, q15;
#define LOADQ(i) q##i = *(const float4*)&tb_[(i) * 4]
    LOADQ(0); LOADQ(1); LOADQ(2); LOADQ(3); LOADQ(4); LOADQ(5); LOADQ(6); LOADQ(7);
    LOADQ(8); LOADQ(9); LOADQ(10); LOADQ(11); LOADQ(12); LOADQ(13); LOADQ(14); LOADQ(15);
#undef LOADQ

    // pass 1 for both t: D = sum_h tc_h * sc_h
    v2f D0a = zero2, D0b = zero2, D1a = zero2, D1b = zero2;
#define P1(i) do { \
      float4 ta = tq0[i]; float4 tbv = tq1[i]; \
      D0a = __builtin_elementwise_fma(lo2(ta),  lo2(q##i), D0a); \
      D0b = __builtin_elementwise_fma(hi2(ta),  hi2(q##i), D0b); \
      D1a = __builtin_elementwise_fma(lo2(tbv), lo2(q##i), D1a); \
      D1b = __builtin_elementwise_fma(hi2(tbv), hi2(q##i), D1b); \
    } while (0)
    P1(0); P1(1); P1(2); P1(3); P1(4); P1(5); P1(6); P1(7);
    P1(8); P1(9); P1(10); P1(11); P1(12); P1(13); P1(14); P1(15);
#undef P1
    v2f Ds0 = D0a + D0b, Ds1 = D1a + D1b;
    float D_0 = Ds0.x + Ds0.y;
    float D_1 = Ds1.x + Ds1.y;

    float mean0  = (A0 + bq.x) * (1.f / HN);
    float var0   = (Qt0 + bq.y + 2.f * D_0) * (1.f / HN) - mean0 * mean0;
    float alpha0 = rsqrtf(var0 + LN_EPS);
    float mean1  = (A1 + bq.x) * (1.f / HN);
    float var1   = (Qt1 + bq.y + 2.f * D_1) * (1.f / HN) - mean1 * mean1;
    float alpha1 = rsqrtf(var1 + LN_EPS);

    v2f m0 = {mean0, mean0}, a0v = {alpha0, alpha0};
    v2f m1 = {mean1, mean1}, a1v = {alpha1, alpha1};
    v2f dt0a = zero2, dt0b = zero2, dt1a = zero2, dt1b = zero2;

    // pass 2 for both t, pure registers
#define P2(i) do { \
      float4 c4 = cgq[i]; float4 b4 = cbq[i]; float4 w4 = swq[i]; \
      float4 ta = tq0[i]; float4 tbv = tq1[i]; \
      { v2f u = lo2(q##i) + lo2(ta);  v2f z = u - m0; v2f P = a0v * lo2(c4); \
        v2f n = __builtin_elementwise_fma(z, P, lo2(b4)); \
        v2f r = __builtin_elementwise_max(n, zero2); \
        dt0a = __builtin_elementwise_fma(r, lo2(w4), dt0a); } \
      { v2f u = hi2(q##i) + hi2(ta);  v2f z = u - m0; v2f P = a0v * hi2(c4); \
        v2f n = __builtin_elementwise_fma(z, P, hi2(b4)); \
        v2f r = __builtin_elementwise_max(n, zero2); \
        dt0b = __builtin_elementwise_fma(r, hi2(w4), dt0b); } \
      { v2f u = lo2(q##i) + lo2(tbv); v2f z = u - m1; v2f P = a1v * lo2(c4); \
        v2f n = __builtin_elementwise_fma(z, P, lo2(b4)); \
        v2f r = __builtin_elementwise_max(n, zero2); \
        dt1a = __builtin_elementwise_fma(r, lo2(w4), dt1a); } \
      { v2f u = hi2(q##i) + hi2(tbv); v2f z = u - m1; v2f P = a1v * hi2(c4); \
        v2f n = __builtin_elementwise_fma(z, P, hi2(b4)); \
        v2f r = __builtin_elementwise_max(n, zero2); \
        dt1b = __builtin_elementwise_fma(r, hi2(w4), dt1b); } \
    } while (0)
    P2(0); P2(1); P2(2); P2(3); P2(4); P2(5); P2(6); P2(7);
    P2(8); P2(9); P2(10); P2(11); P2(12); P2(13); P2(14); P2(15);
#undef P2
    v2f dd0 = dt0a + dt0b, dd1 = dt1a + dt1b;
    float dot0 = dd0.x + dd0.y;
    float dot1 = dd1.x + dd1.y;
    float score0 = 1.f / (1.f + __expf(-(dot0 + simb0)));
    float score1 = 1.f / (1.f + __expf(-(dot1 + simb0)));
    out_scores[rt0 * SN + s] = score0;
    out_scores[rt1 * SN + s] = score1;

    if (c < 3) {
      int dst = ((c + 1) & 1) * CHUNKDW;
      *(float4*)&tile[dst + d0] = p0;
      *(float4*)&tile[dst + d1] = p1;
    }
    __syncthreads();
  }
}

// ---------------- Kernel 3a: partial transfer (split-s) ----------------
__global__ __launch_bounds__(256, 4) void k_xfer(
    const float* __restrict__ scores, const float* __restrict__ s_ad,
    float* __restrict__ xpart, float* __restrict__ epart)
{
  __shared__ float eLDS[4][16][64];
  __shared__ float part[4][16][64];
  __shared__ float esum[4][16];
  int tid = threadIdx.x;
  int w = __builtin_amdgcn_readfirstlane(tid >> 6);
  int lane = tid & 63;
  int sblk = blockIdx.x & 3;
  int tblk = (blockIdx.x >> 2) & 63;
  int b    = blockIdx.x >> 8;
  int t0 = tblk * 16;
  int soff = sblk * 256 + w * 64;

#pragma unroll 4
  for (int t = 0; t < 16; ++t) {
    int rt = __builtin_amdgcn_readfirstlane(b * TN + t0 + t);
    float ev = __expf(scores[rt * SN + soff + lane]);
    eLDS[w][t][lane] = ev;
    float es = wave_sum(ev);
    if (lane == 0) esum[w][t] = es;
  }

  const float* sadb = s_ad + b * SN * HN;
  float acc[16];
#pragma unroll
  for (int t = 0; t < 16; ++t) acc[t] = 0.f;
#pragma unroll 4
  for (int si4 = 0; si4 < 16; ++si4) {
    int sbase = soff + si4 * 4;
    float sv0 = sadb[(sbase + 0) * HN + lane];
    float sv1 = sadb[(sbase + 1) * HN + lane];
    float sv2 = sadb[(sbase + 2) * HN + lane];
    float sv3 = sadb[(sbase + 3) * HN + lane];
#pragma unroll
    for (int t = 0; t < 16; ++t) {
      float4 e4 = *(const float4*)&eLDS[w][t][si4 * 4];
      acc[t] = fmaf(e4.x, sv0, acc[t]);
      acc[t] = fmaf(e4.y, sv1, acc[t]);
      acc[t] = fmaf(e4.z, sv2, acc[t]);
      acc[t] = fmaf(e4.w, sv3, acc[t]);
    }
  }

#pragma unroll
  for (int t = 0; t < 16; ++t) part[w][t][lane] = acc[t];
  __syncthreads();
#pragma unroll
  for (int k = 0; k < 4; ++k) {
    int c2 = tid + k * 256;
    int t = c2 >> 6, h = c2 & 63;
    float sum = part[0][t][h] + part[1][t][h] + part[2][t][h] + part[3][t][h];
    int rt = b * TN + t0 + t;
    xpart[(rt * 4 + sblk) * HN + h] = sum;
  }
  if (tid < 16) {
    float es = esum[0][tid] + esum[1][tid] + esum[2][tid] + esum[3][tid];
    int rt = b * TN + t0 + tid;
    epart[rt * 4 + sblk] = es;
  }
}

// ---------------- Kernel 3b: final combine + gate ----------------
__global__ __launch_bounds__(256) void k_final(
    const float* __restrict__ xpart, const float* __restrict__ epart,
    const float* __restrict__ t_ad, const float* __restrict__ tstats,
    float* __restrict__ out_adapted)
{
  int tid = threadIdx.x;
  int tl = tid >> 6, h = tid & 63;
  int rt = blockIdx.x * 4 + tl;       // 0..2047
  float x = xpart[(rt * 4 + 0) * HN + h] + xpart[(rt * 4 + 1) * HN + h]
          + xpart[(rt * 4 + 2) * HN + h] + xpart[(rt * 4 + 3) * HN + h];
  float es = epart[rt * 4 + 0] + epart[rt * 4 + 1]
           + epart[rt * 4 + 2] + epart[rt * 4 + 3];
  float tr = x / es;
  float gate = tstats[rt * 3 + 2];
  float tad = t_ad[rt * HN + h];
  out_adapted[rt * HN + h] = tad * (1.f - gate) + tr * gate;
}

extern "C" void kernel_launch(void* const* d_in, const int* in_sizes, int n_in,
                              void* d_out, int out_size, void* d_ws, size_t ws_size,
                              hipStream_t stream) {
  const float* src   = (const float*)d_in[0];
  const float* tgt   = (const float*)d_in[1];
  const float* sW1   = (const float*)d_in[2];
  const float* sb1   = (const float*)d_in[3];
  const float* sg    = (const float*)d_in[4];
  const float* sbeta = (const float*)d_in[5];
  const float* sW2   = (const float*)d_in[6];
  const float* sb2   = (const float*)d_in[7];
  const float* tW1   = (const float*)d_in[8];
  const float* tb1   = (const float*)d_in[9];
  const float* tg    = (const float*)d_in[10];
  const float* tbeta = (const float*)d_in[11];
  const float* tW2   = (const float*)d_in[12];
  const float* tb2   = (const float*)d_in[13];
  const float* cW    = (const float*)d_in[14];
  const float* cb    = (const float*)d_in[15];
  const float* cg    = (const float*)d_in[16];
  const float* cbeta = (const float*)d_in[17];
  const float* simW  = (const float*)d_in[18];
  const float* simb  = (const float*)d_in[19];

  float* ws     = (float*)d_ws;
  float* s_ad   = ws;               // 131072
  float* sc     = ws + 131072;      // 131072
  float* sstats = ws + 262144;      // 4096
  float* t_ad   = ws + 266240;      // 131072
  float* tc     = ws + 397312;      // 131072
  float* tstats = ws + 528384;      // 6144
  float* xpart  = ws + 534528;      // 524288
  float* epart  = ws + 1058816;     // 8192

  float* out_adapted = (float*)d_out;            // B*T*H
  float* out_scores  = (float*)d_out + 131072;   // B*T*S

  hipLaunchKernelGGL(k_adapters, dim3(1024), dim3(256), 0, stream,
                     src, tgt, sW1, sb1, sg, sbeta, sW2, sb2,
                     tW1, tb1, tg, tbeta, tW2, tb2, cW, cb,
                     s_ad, sc, sstats, t_ad, tc, tstats);
  hipLaunchKernelGGL(k_scores, dim3(BN * 64 * 4), dim3(512), 0, stream,
                     cg, cbeta, simW, simb, sc, sstats, tc, tstats, out_scores);
  hipLaunchKernelGGL(k_xfer, dim3(BN * 64 * 4), dim3(256), 0, stream,
                     out_scores, s_ad, xpart, epart);
  hipLaunchKernelGGL(k_final, dim3(512), dim3(256), 0, stream,
                     xpart, epart, t_ad, tstats, out_adapted);
}

// Round 9
// 151.730 us; speedup vs baseline: 1.3796x; 1.1164x over previous
//
#include <hip/hip_runtime.h>
#include <math.h>

#define BN 2
#define SN 1024
#define TN 1024
#define DS 128
#define DT 64
#define HN 64
#define LN_EPS 1e-5f

typedef float v2f __attribute__((ext_vector_type(2)));

__device__ __forceinline__ float wave_sum(float v) {
#pragma unroll
  for (int m = 32; m >= 1; m >>= 1) v += __shfl_xor(v, m, 64);
  return v;
}

__device__ __forceinline__ v2f lo2(float4 v) { v2f r = {v.x, v.y}; return r; }
__device__ __forceinline__ v2f hi2(float4 v) { v2f r = {v.z, v.w}; return r; }

// ---------------- Kernel 1: both adapters in one launch ----------------
__global__ __launch_bounds__(256) void k_adapters(
    const float* __restrict__ src, const float* __restrict__ tgt,
    const float* __restrict__ sW1, const float* __restrict__ sb1,
    const float* __restrict__ sg, const float* __restrict__ sbeta,
    const float* __restrict__ sW2, const float* __restrict__ sb2,
    const float* __restrict__ tW1, const float* __restrict__ tb1,
    const float* __restrict__ tg, const float* __restrict__ tbeta,
    const float* __restrict__ tW2, const float* __restrict__ tb2,
    const float* __restrict__ cW, const float* __restrict__ cb,
    float* __restrict__ s_ad, float* __restrict__ sc, float* __restrict__ sstats,
    float* __restrict__ t_ad, float* __restrict__ tc, float* __restrict__ tstats)
{
  __shared__ float xbuf[4][DS];
  __shared__ float rbuf[4][HN];
  int w = threadIdx.x >> 6, lane = threadIdx.x & 63;

  if (blockIdx.x < 512) {
    int row = blockIdx.x * 4 + w;  // 0..2047
    xbuf[w][lane]      = src[row * DS + lane];
    xbuf[w][lane + 64] = src[row * DS + 64 + lane];
    float a0 = 0.f, a1 = 0.f, a2_ = 0.f, a3 = 0.f;
#pragma unroll 8
    for (int k = 0; k < DS; k += 4) {
      a0  = fmaf(xbuf[w][k + 0], sW1[(k + 0) * HN + lane], a0);
      a1  = fmaf(xbuf[w][k + 1], sW1[(k + 1) * HN + lane], a1);
      a2_ = fmaf(xbuf[w][k + 2], sW1[(k + 2) * HN + lane], a2_);
      a3  = fmaf(xbuf[w][k + 3], sW1[(k + 3) * HN + lane], a3);
    }
    float h1 = ((a0 + a1) + (a2_ + a3)) + sb1[lane];
    float s1 = wave_sum(h1), s2 = wave_sum(h1 * h1);
    float m = s1 * (1.f / HN);
    float var = s2 * (1.f / HN) - m * m;
    float r = fmaxf(0.f, (h1 - m) * rsqrtf(var + LN_EPS) * sg[lane] + sbeta[lane]);
    rbuf[w][lane] = r;
    float b0 = 0.f, b1 = 0.f, b2 = 0.f, b3 = 0.f;
#pragma unroll 4
    for (int j = 0; j < HN; j += 4) {
      b0 = fmaf(rbuf[w][j + 0], sW2[(j + 0) * HN + lane], b0);
      b1 = fmaf(rbuf[w][j + 1], sW2[(j + 1) * HN + lane], b1);
      b2 = fmaf(rbuf[w][j + 2], sW2[(j + 2) * HN + lane], b2);
      b3 = fmaf(rbuf[w][j + 3], sW2[(j + 3) * HN + lane], b3);
    }
    float a2 = ((b0 + b1) + (b2 + b3)) + sb2[lane];
    s_ad[row * HN + lane] = a2;
    rbuf[w][lane] = a2;
    float c0 = 0.f, c1 = 0.f, c2 = 0.f, c3 = 0.f;
#pragma unroll 4
    for (int j = 0; j < HN; j += 4) {
      c0 = fmaf(rbuf[w][j + 0], cW[(HN + j + 0) * HN + lane], c0);
      c1 = fmaf(rbuf[w][j + 1], cW[(HN + j + 1) * HN + lane], c1);
      c2 = fmaf(rbuf[w][j + 2], cW[(HN + j + 2) * HN + lane], c2);
      c3 = fmaf(rbuf[w][j + 3], cW[(HN + j + 3) * HN + lane], c3);
    }
    float scv = (c0 + c1) + (c2 + c3);
    sc[row * HN + lane] = scv;
    float bs = wave_sum(scv), qs = wave_sum(scv * scv);
    if (lane == 0) { sstats[row * 2] = bs; sstats[row * 2 + 1] = qs; }
  } else {
    int row = (blockIdx.x - 512) * 4 + w;  // 0..2047
    xbuf[w][lane] = tgt[row * DT + lane];
    float a0 = 0.f, a1 = 0.f, a2_ = 0.f, a3 = 0.f;
#pragma unroll 4
    for (int k = 0; k < DT; k += 4) {
      a0  = fmaf(xbuf[w][k + 0], tW1[(k + 0) * HN + lane], a0);
      a1  = fmaf(xbuf[w][k + 1], tW1[(k + 1) * HN + lane], a1);
      a2_ = fmaf(xbuf[w][k + 2], tW1[(k + 2) * HN + lane], a2_);
      a3  = fmaf(xbuf[w][k + 3], tW1[(k + 3) * HN + lane], a3);
    }
    float h1 = ((a0 + a1) + (a2_ + a3)) + tb1[lane];
    float s1 = wave_sum(h1), s2 = wave_sum(h1 * h1);
    float m = s1 * (1.f / HN);
    float var = s2 * (1.f / HN) - m * m;
    float r = fmaxf(0.f, (h1 - m) * rsqrtf(var + LN_EPS) * tg[lane] + tbeta[lane]);
    rbuf[w][lane] = r;
    float b0 = 0.f, b1 = 0.f, b2 = 0.f, b3 = 0.f;
#pragma unroll 4
    for (int j = 0; j < HN; j += 4) {
      b0 = fmaf(rbuf[w][j + 0], tW2[(j + 0) * HN + lane], b0);
      b1 = fmaf(rbuf[w][j + 1], tW2[(j + 1) * HN + lane], b1);
      b2 = fmaf(rbuf[w][j + 2], tW2[(j + 2) * HN + lane], b2);
      b3 = fmaf(rbuf[w][j + 3], tW2[(j + 3) * HN + lane], b3);
    }
    float a2 = ((b0 + b1) + (b2 + b3)) + tb2[lane];
    t_ad[row * HN + lane] = a2;
    float asum = wave_sum(a2);
    float gate = 1.f / (1.f + __expf(-asum * (1.f / HN)));
    rbuf[w][lane] = a2;
    float c0 = 0.f, c1 = 0.f, c2 = 0.f, c3 = 0.f;
#pragma unroll 4
    for (int j = 0; j < HN; j += 4) {
      c0 = fmaf(rbuf[w][j + 0], cW[(j + 0) * HN + lane], c0);
      c1 = fmaf(rbuf[w][j + 1], cW[(j + 1) * HN + lane], c1);
      c2 = fmaf(rbuf[w][j + 2], cW[(j + 2) * HN + lane], c2);
      c3 = fmaf(rbuf[w][j + 3], cW[(j + 3) * HN + lane], c3);
    }
    float tcv = ((c0 + c1) + (c2 + c3)) + cb[lane];
    tc[row * HN + lane] = tcv;
    float A = wave_sum(tcv), Q = wave_sum(tcv * tcv);
    if (lane == 0) { tstats[row * 3] = A; tstats[row * 3 + 1] = Q; tstats[row * 3 + 2] = gate; }
  }
}

// ---------------- Kernel 2: scores v9 ----------------
// Max-occupancy single-chunk: block = 8 waves x 2t/wave x one 64-s tile.
// Stride-68 row layout (0 conflicts measured in R8), staged once, ONE
// barrier, no dbuf. Grid 2048 blocks -> 4 resident blocks/CU (32 waves) +
// 2x oversubscription to fill barrier/tail bubbles.
#define ROWDW 68
__global__ __launch_bounds__(512) void k_scores(
    const float* __restrict__ cg, const float* __restrict__ cbeta,
    const float* __restrict__ simW, const float* __restrict__ simb,
    const float* __restrict__ sc, const float* __restrict__ sstats,
    const float* __restrict__ tc, const float* __restrict__ tstats,
    float* __restrict__ out_scores)
{
  __shared__ float tile[64 * ROWDW];   // 17.4 KB
  int tid = threadIdx.x;
  int w = tid >> 6, lane = tid & 63;
  int sblk = blockIdx.x & 15;                // 16 s-chunks of 64
  int tblk = (blockIdx.x >> 4) & 63;         // 64 t-blocks of 16
  int b    = blockIdx.x >> 10;
  int t0 = tblk * 16 + w * 2;
  int rt0 = __builtin_amdgcn_readfirstlane(b * TN + t0);
  int rt1 = rt0 + 1;
  int s0 = sblk * 64;

  float A0  = tstats[rt0 * 3 + 0];
  float Qt0 = tstats[rt0 * 3 + 1];
  float A1  = tstats[rt1 * 3 + 0];
  float Qt1 = tstats[rt1 * 3 + 1];
  const float4* tq0 = (const float4*)(tc + rt0 * HN);  // wave-uniform
  const float4* tq1 = (const float4*)(tc + rt1 * HN);
  const float4* cgq = (const float4*)cg;
  const float4* cbq = (const float4*)cbeta;
  const float4* swq = (const float4*)simW;
  float simb0 = simb[0];

  const float4* scg = (const float4*)(sc + b * SN * HN);

  // stage 64 rows x 16 float4: 1024 cells, 2 per thread
  {
    int r0s = tid >> 4, gs = tid & 15;        // rows 0..31
    float4 v0 = scg[(s0 + r0s) * 16 + gs];
    float4 v1 = scg[(s0 + r0s + 32) * 16 + gs];
    *(float4*)&tile[r0s * ROWDW + gs * 4] = v0;
    *(float4*)&tile[(r0s + 32) * ROWDW + gs * 4] = v1;
  }
  __syncthreads();

  const v2f zero2 = {0.f, 0.f};
  const float* tb_ = &tile[lane * ROWDW];
  int s = s0 + lane;
  float2 bq = *(const float2*)&sstats[(b * SN + s) * 2];

  // pass 1 for both t: D = sum_h tc_h * sc_h (16 immediate-offset b128)
  v2f D0a = zero2, D0b = zero2, D1a = zero2, D1b = zero2;
#pragma unroll
  for (int g = 0; g < 16; ++g) {
    float4 v = *(const float4*)&tb_[g * 4];
    float4 ta = tq0[g]; float4 tbv = tq1[g];
    D0a = __builtin_elementwise_fma(lo2(ta),  lo2(v), D0a);
    D0b = __builtin_elementwise_fma(hi2(ta),  hi2(v), D0b);
    D1a = __builtin_elementwise_fma(lo2(tbv), lo2(v), D1a);
    D1b = __builtin_elementwise_fma(hi2(tbv), hi2(v), D1b);
  }
  v2f Ds0 = D0a + D0b, Ds1 = D1a + D1b;
  float D_0 = Ds0.x + Ds0.y;
  float D_1 = Ds1.x + Ds1.y;

  float mean0  = (A0 + bq.x) * (1.f / HN);
  float var0   = (Qt0 + bq.y + 2.f * D_0) * (1.f / HN) - mean0 * mean0;
  float alpha0 = rsqrtf(var0 + LN_EPS);
  float mean1  = (A1 + bq.x) * (1.f / HN);
  float var1   = (Qt1 + bq.y + 2.f * D_1) * (1.f / HN) - mean1 * mean1;
  float alpha1 = rsqrtf(var1 + LN_EPS);

  v2f m0 = {mean0, mean0}, a0v = {alpha0, alpha0};
  v2f m1 = {mean1, mean1}, a1v = {alpha1, alpha1};
  v2f dt0a = zero2, dt0b = zero2, dt1a = zero2, dt1b = zero2;

  // pass 2 for both t
#pragma unroll
  for (int g = 0; g < 16; ++g) {
    float4 v  = *(const float4*)&tb_[g * 4];
    float4 c4 = cgq[g]; float4 b4 = cbq[g]; float4 w4 = swq[g];
    float4 ta = tq0[g]; float4 tbv = tq1[g];
    { v2f u = lo2(v) + lo2(ta);  v2f z = u - m0; v2f P = a0v * lo2(c4);
      v2f n = __builtin_elementwise_fma(z, P, lo2(b4));
      v2f r = __builtin_elementwise_max(n, zero2);
      dt0a = __builtin_elementwise_fma(r, lo2(w4), dt0a); }
    { v2f u = hi2(v) + hi2(ta);  v2f z = u - m0; v2f P = a0v * hi2(c4);
      v2f n = __builtin_elementwise_fma(z, P, hi2(b4));
      v2f r = __builtin_elementwise_max(n, zero2);
      dt0b = __builtin_elementwise_fma(r, hi2(w4), dt0b); }
    { v2f u = lo2(v) + lo2(tbv); v2f z = u - m1; v2f P = a1v * lo2(c4);
      v2f n = __builtin_elementwise_fma(z, P, lo2(b4));
      v2f r = __builtin_elementwise_max(n, zero2);
      dt1a = __builtin_elementwise_fma(r, lo2(w4), dt1a); }
    { v2f u = hi2(v) + hi2(tbv); v2f z = u - m1; v2f P = a1v * hi2(c4);
      v2f n = __builtin_elementwise_fma(z, P, hi2(b4));
      v2f r = __builtin_elementwise_max(n, zero2);
      dt1b = __builtin_elementwise_fma(r, hi2(w4), dt1b); }
  }
  v2f dd0 = dt0a + dt0b, dd1 = dt1a + dt1b;
  float dot0 = dd0.x + dd0.y;
  float dot1 = dd1.x + dd1.y;
  float score0 = 1.f / (1.f + __expf(-(dot0 + simb0)));
  float score1 = 1.f / (1.f + __expf(-(dot1 + simb0)));
  out_scores[rt0 * SN + s] = score0;
  out_scores[rt1 * SN + s] = score1;
}

// ---------------- Kernel 3a: partial transfer (split-s) ----------------
__global__ __launch_bounds__(256, 4) void k_xfer(
    const float* __restrict__ scores, const float* __restrict__ s_ad,
    float* __restrict__ xpart, float* __restrict__ epart)
{
  __shared__ float eLDS[4][16][64];
  __shared__ float part[4][16][64];
  __shared__ float esum[4][16];
  int tid = threadIdx.x;
  int w = __builtin_amdgcn_readfirstlane(tid >> 6);
  int lane = tid & 63;
  int sblk = blockIdx.x & 3;
  int tblk = (blockIdx.x >> 2) & 63;
  int b    = blockIdx.x >> 8;
  int t0 = tblk * 16;
  int soff = sblk * 256 + w * 64;

#pragma unroll 4
  for (int t = 0; t < 16; ++t) {
    int rt = __builtin_amdgcn_readfirstlane(b * TN + t0 + t);
    float ev = __expf(scores[rt * SN + soff + lane]);
    eLDS[w][t][lane] = ev;
    float es = wave_sum(ev);
    if (lane == 0) esum[w][t] = es;
  }

  const float* sadb = s_ad + b * SN * HN;
  float acc[16];
#pragma unroll
  for (int t = 0; t < 16; ++t) acc[t] = 0.f;
#pragma unroll 4
  for (int si4 = 0; si4 < 16; ++si4) {
    int sbase = soff + si4 * 4;
    float sv0 = sadb[(sbase + 0) * HN + lane];
    float sv1 = sadb[(sbase + 1) * HN + lane];
    float sv2 = sadb[(sbase + 2) * HN + lane];
    float sv3 = sadb[(sbase + 3) * HN + lane];
#pragma unroll
    for (int t = 0; t < 16; ++t) {
      float4 e4 = *(const float4*)&eLDS[w][t][si4 * 4];
      acc[t] = fmaf(e4.x, sv0, acc[t]);
      acc[t] = fmaf(e4.y, sv1, acc[t]);
      acc[t] = fmaf(e4.z, sv2, acc[t]);
      acc[t] = fmaf(e4.w, sv3, acc[t]);
    }
  }

#pragma unroll
  for (int t = 0; t < 16; ++t) part[w][t][lane] = acc[t];
  __syncthreads();
#pragma unroll
  for (int k = 0; k < 4; ++k) {
    int c2 = tid + k * 256;
    int t = c2 >> 6, h = c2 & 63;
    float sum = part[0][t][h] + part[1][t][h] + part[2][t][h] + part[3][t][h];
    int rt = b * TN + t0 + t;
    xpart[(rt * 4 + sblk) * HN + h] = sum;
  }
  if (tid < 16) {
    float es = esum[0][tid] + esum[1][tid] + esum[2][tid] + esum[3][tid];
    int rt = b * TN + t0 + tid;
    epart[rt * 4 + sblk] = es;
  }
}

// ---------------- Kernel 3b: final combine + gate ----------------
__global__ __launch_bounds__(256) void k_final(
    const float* __restrict__ xpart, const float* __restrict__ epart,
    const float* __restrict__ t_ad, const float* __restrict__ tstats,
    float* __restrict__ out_adapted)
{
  int tid = threadIdx.x;
  int tl = tid >> 6, h = tid & 63;
  int rt = blockIdx.x * 4 + tl;       // 0..2047
  float x = xpart[(rt * 4 + 0) * HN + h] + xpart[(rt * 4 + 1) * HN + h]
          + xpart[(rt * 4 + 2) * HN + h] + xpart[(rt * 4 + 3) * HN + h];
  float es = epart[rt * 4 + 0] + epart[rt * 4 + 1]
           + epart[rt * 4 + 2] + epart[rt * 4 + 3];
  float tr = x / es;
  float gate = tstats[rt * 3 + 2];
  float tad = t_ad[rt * HN + h];
  out_adapted[rt * HN + h] = tad * (1.f - gate) + tr * gate;
}

extern "C" void kernel_launch(void* const* d_in, const int* in_sizes, int n_in,
                              void* d_out, int out_size, void* d_ws, size_t ws_size,
                              hipStream_t stream) {
  const float* src   = (const float*)d_in[0];
  const float* tgt   = (const float*)d_in[1];
  const float* sW1   = (const float*)d_in[2];
  const float* sb1   = (const float*)d_in[3];
  const float* sg    = (const float*)d_in[4];
  const float* sbeta = (const float*)d_in[5];
  const float* sW2   = (const float*)d_in[6];
  const float* sb2   = (const float*)d_in[7];
  const float* tW1   = (const float*)d_in[8];
  const float* tb1   = (const float*)d_in[9];
  const float* tg    = (const float*)d_in[10];
  const float* tbeta = (const float*)d_in[11];
  const float* tW2   = (const float*)d_in[12];
  const float* tb2   = (const float*)d_in[13];
  const float* cW    = (const float*)d_in[14];
  const float* cb    = (const float*)d_in[15];
  const float* cg    = (const float*)d_in[16];
  const float* cbeta = (const float*)d_in[17];
  const float* simW  = (const float*)d_in[18];
  const float* simb  = (const float*)d_in[19];

  float* ws     = (float*)d_ws;
  float* s_ad   = ws;               // 131072
  float* sc     = ws + 131072;      // 131072
  float* sstats = ws + 262144;      // 4096
  float* t_ad   = ws + 266240;      // 131072
  float* tc     = ws + 397312;      // 131072
  float* tstats = ws + 528384;      // 6144
  float* xpart  = ws + 534528;      // 524288
  float* epart  = ws + 1058816;     // 8192

  float* out_adapted = (float*)d_out;            // B*T*H
  float* out_scores  = (float*)d_out + 131072;   // B*T*S

  hipLaunchKernelGGL(k_adapters, dim3(1024), dim3(256), 0, stream,
                     src, tgt, sW1, sb1, sg, sbeta, sW2, sb2,
                     tW1, tb1, tg, tbeta, tW2, tb2, cW, cb,
                     s_ad, sc, sstats, t_ad, tc, tstats);
  hipLaunchKernelGGL(k_scores, dim3(BN * 64 * 16), dim3(512), 0, stream,
                     cg, cbeta, simW, simb, sc, sstats, tc, tstats, out_scores);
  hipLaunchKernelGGL(k_xfer, dim3(BN * 64 * 4), dim3(256), 0, stream,
                     out_scores, s_ad, xpart, epart);
  hipLaunchKernelGGL(k_final, dim3(512), dim3(256), 0, stream,
                     xpart, epart, t_ad, tstats, out_adapted);
}